// Round 5
// baseline (160.059 us; speedup 1.0000x reference)
//
#include <hip/hip_runtime.h>
#include <hip/hip_bf16.h>
#include <stdint.h>
#include <stddef.h>

// Problem constants
#define BT_TOK   32768      // B*T
#define IN_DIM   512
#define OUT_DIM  512
#define QDIM     32
#define NG       8
#define NV       8
#define VD       64
#define EPS_G    1e-10f

#define MT       64         // tokens per block (= lanes per wave)
#define NW       8          // waves per block = K-split factor

typedef float f32x2 __attribute__((ext_vector_type(2)));   // native vector for nontemporal store

// ---------------------------------------------------------------------------
// Kernel A: paired codebook-output table (UNCHANGED — bitwise-identical P2)
// P2[p][i*8+j][o] = cb[2p][i]@W_post[2p*64:...] + cb[2p+1][j]@W_post[...]
// bf16, 4*64*512 = 256 KB in d_ws. Rebuilt every call (ws is re-poisoned).
// ---------------------------------------------------------------------------
__global__ __launch_bounds__(256) void build_p2(
    const float* __restrict__ codebook,   // (8,8,64)
    const float* __restrict__ W_post,     // (512,512)
    __hip_bfloat16* __restrict__ P2)
{
    const int b  = blockIdx.x;     // 0..255
    const int p  = b >> 6;         // pair 0..3
    const int ij = b & 63;
    const int i  = ij >> 3, j = ij & 7;
    const int t  = threadIdx.x;    // 0..255

    const float* ca  = codebook + ((size_t)(2 * p) * NV + i) * VD;
    const float* cbp = codebook + ((size_t)(2 * p + 1) * NV + j) * VD;
    const float* wa  = W_post + (size_t)(2 * p) * VD * OUT_DIM;
    const float* wb  = W_post + (size_t)(2 * p + 1) * VD * OUT_DIM;

    float a0 = 0.f, a1 = 0.f;
#pragma unroll 8
    for (int d = 0; d < VD; ++d) {
        const float sa = ca[d];            // block-uniform -> scalar
        const float sb = cbp[d];
        a0 += sa * wa[(size_t)d * OUT_DIM + t]       + sb * wb[(size_t)d * OUT_DIM + t];
        a1 += sa * wa[(size_t)d * OUT_DIM + t + 256] + sb * wb[(size_t)d * OUT_DIM + t + 256];
    }
    __hip_bfloat16* dst = P2 + ((size_t)(p * 64 + ij)) * OUT_DIM;
    dst[t]       = __float2bfloat16(a0);
    dst[t + 256] = __float2bfloat16(a1);
}

// ---------------------------------------------------------------------------
// Kernel B: h = x@W_pre+b_pre ; logits = h@W_proj+b_proj ;
//           idx = argmax(logits+gumbel(u)) ; emit packed pair-indices.
// Block: 512 threads = 8 waves, 64 tokens. lane = token; wave = K-eighth.
//
// ROUND-4/5 CHANGE: round 3's pre-issued loads were re-sunk by the scheduler
// (VGPR_Count stayed 52; dur unchanged 42us; VALUBusy 23% => 77% latency
// stall). Now the load block is PINNED with sched_barrier(0): all 18 global
// loads (u0,u1,xv[0..15]) must issue before any LDS op, so each wave exposes
// ~1 HBM latency per block instead of ~12. ~110-120 VGPR, within the 128
// budget of __launch_bounds__(512,4) -> occupancy unchanged (4 waves/SIMD).
// Arithmetic order is bitwise-identical to rounds 0-3.
// (Round 4 bench was an infra failure — this is the same kernel resubmitted.)
// ---------------------------------------------------------------------------
__global__ __launch_bounds__(512, 4) void fused_logits(
    const float* __restrict__ x,        // (BT,512)
    const float* __restrict__ W_pre,    // (512,32)
    const float* __restrict__ b_pre,    // (32)
    const float* __restrict__ W_proj,   // (32,64)
    const float* __restrict__ b_proj,   // (64)
    const float* __restrict__ u,        // (BT,64)
    uint32_t* __restrict__ pidx_pack)   // (BT) packed p0|p1<<8|p2<<16|p3<<24
{
    // Per-wave arena: rows 0..63 (token), 36-float stride. Used first as x
    // stage (cols 0..31 = 32 k-values), then overwritten by partial-h slice.
    __shared__ float Hs4[NW][MT][36];
    __shared__ int   idxs_s[NG][MT];    // argmax per (group, token)

    const int t    = threadIdx.x;
    const int lane = t & 63;                                   // token within block
    const int w    = __builtin_amdgcn_readfirstlane(t >> 6);   // wave id = K-eighth / group
    const int tokbase = blockIdx.x * MT;
    const int gtok    = tokbase + lane;

    const int tsub = lane >> 3;          // token sub-index within 8-token group
    const int c4   = lane & 7;           // 16B chunk within the 128B row slice
    const float* xws = x + (size_t)tokbase * IN_DIM + w * 64;  // wave k-slice base

    // ---- pre-issue EVERYTHING, then PIN with sched_barrier(0) -------------
    const float4 u0 = *(const float4*)&u[(size_t)gtok * 64 + w * 8];
    const float4 u1 = *(const float4*)&u[(size_t)gtok * 64 + w * 8 + 4];

    float4 xv[16];
#pragma unroll
    for (int s = 0; s < 2; ++s)
#pragma unroll
        for (int i = 0; i < 8; ++i)
            xv[s * 8 + i] = *(const float4*)(xws + (size_t)(i * 8 + tsub) * IN_DIM
                                             + s * 32 + c4 * 4);

    // Nothing may move across this point: the 18 loads above stay issued
    // back-to-back, and the ds_writes below cannot hoist above it.
    __builtin_amdgcn_sched_barrier(0);

    // ---------------- Phase 1: partial h over K-slice [w*64, w*64+64) --------
    float acc[QDIM];
#pragma unroll
    for (int j = 0; j < QDIM; ++j) acc[j] = 0.f;

#pragma unroll
    for (int s = 0; s < 2; ++s) {        // 2 stages of 32 k
        // stage: write pre-loaded tile slice to this wave's arena
#pragma unroll
        for (int i = 0; i < 8; ++i)
            *(float4*)&Hs4[w][i * 8 + tsub][c4 * 4] = xv[s * 8 + i];

        // Consume: lane reads ITS token's 32 staged k-values; W_pre rows are
        // wave-uniform -> scalar loads. k ascending (bitwise-identical h).
        const float* wbase = W_pre + (size_t)(w * 64 + s * 32) * QDIM;
#pragma unroll
        for (int k4 = 0; k4 < 8; ++k4) {
            const float4 xr = *(const float4*)&Hs4[w][lane][k4 * 4];
            const float xk4[4] = {xr.x, xr.y, xr.z, xr.w};
#pragma unroll
            for (int e = 0; e < 4; ++e) {
                const float xvv = xk4[e];
                const float4* wr = (const float4*)(wbase + (size_t)(k4 * 4 + e) * QDIM); // uniform
                const float4 w0 = wr[0], w1 = wr[1], w2 = wr[2], w3 = wr[3];
                const float4 w4 = wr[4], w5 = wr[5], w6 = wr[6], w7 = wr[7];
                acc[0]  += xvv * w0.x; acc[1]  += xvv * w0.y; acc[2]  += xvv * w0.z; acc[3]  += xvv * w0.w;
                acc[4]  += xvv * w1.x; acc[5]  += xvv * w1.y; acc[6]  += xvv * w1.z; acc[7]  += xvv * w1.w;
                acc[8]  += xvv * w2.x; acc[9]  += xvv * w2.y; acc[10] += xvv * w2.z; acc[11] += xvv * w2.w;
                acc[12] += xvv * w3.x; acc[13] += xvv * w3.y; acc[14] += xvv * w3.z; acc[15] += xvv * w3.w;
                acc[16] += xvv * w4.x; acc[17] += xvv * w4.y; acc[18] += xvv * w4.z; acc[19] += xvv * w4.w;
                acc[20] += xvv * w5.x; acc[21] += xvv * w5.y; acc[22] += xvv * w5.z; acc[23] += xvv * w5.w;
                acc[24] += xvv * w6.x; acc[25] += xvv * w6.y; acc[26] += xvv * w6.z; acc[27] += xvv * w6.w;
                acc[28] += xvv * w7.x; acc[29] += xvv * w7.y; acc[30] += xvv * w7.z; acc[31] += xvv * w7.w;
            }
        }
        // Stage-1 ds_writes overwrite rows just read: same-wave DS ops are
        // in-order; compiler preserves may-alias store-after-load order.
    }

    // write partials over the stage data (b128; stride-36 layout)
#pragma unroll
    for (int j4 = 0; j4 < 8; ++j4)
        *(float4*)&Hs4[w][lane][j4 * 4] =
            make_float4(acc[j4 * 4], acc[j4 * 4 + 1], acc[j4 * 4 + 2], acc[j4 * 4 + 3]);
    __syncthreads();

    // reduce 8 K-slices in place (each cell owned by exactly one thread)
#pragma unroll
    for (int r = 0; r < 4; ++r) {
        const int id  = t + 512 * r;          // 2048 (tok,j) cells
        const int tok = id >> 5;
        const int j   = id & 31;
        float h = b_pre[j];
#pragma unroll
        for (int q = 0; q < NW; ++q) h += Hs4[q][tok][j];
        Hs4[0][tok][j] = h;
    }
    __syncthreads();

    // ---------------- Phase 2: logits + gumbel + argmax (wave w -> group w) ---
    float h[QDIM];
#pragma unroll
    for (int j4 = 0; j4 < 8; ++j4) {
        const float4 v = *(const float4*)&Hs4[0][lane][j4 * 4];
        h[j4 * 4] = v.x; h[j4 * 4 + 1] = v.y; h[j4 * 4 + 2] = v.z; h[j4 * 4 + 3] = v.w;
    }

    {
        const int g = w;                                // wave-uniform group
        const float4 b0 = *(const float4*)&b_proj[g * 8];
        const float4 b1 = *(const float4*)&b_proj[g * 8 + 4];
        float lg[8] = {b0.x, b0.y, b0.z, b0.w, b1.x, b1.y, b1.z, b1.w};

#pragma unroll
        for (int j = 0; j < QDIM; ++j) {
            const float hv = h[j];
            const float4 a0 = *(const float4*)&W_proj[(size_t)j * 64 + g * 8];     // uniform
            const float4 a1 = *(const float4*)&W_proj[(size_t)j * 64 + g * 8 + 4]; // uniform
            lg[0] += hv * a0.x; lg[1] += hv * a0.y; lg[2] += hv * a0.z; lg[3] += hv * a0.w;
            lg[4] += hv * a1.x; lg[5] += hv * a1.y; lg[6] += hv * a1.z; lg[7] += hv * a1.w;
        }

        float y[8];
        y[0] = lg[0] - logf(-logf(u0.x + EPS_G) + EPS_G);
        y[1] = lg[1] - logf(-logf(u0.y + EPS_G) + EPS_G);
        y[2] = lg[2] - logf(-logf(u0.z + EPS_G) + EPS_G);
        y[3] = lg[3] - logf(-logf(u0.w + EPS_G) + EPS_G);
        y[4] = lg[4] - logf(-logf(u1.x + EPS_G) + EPS_G);
        y[5] = lg[5] - logf(-logf(u1.y + EPS_G) + EPS_G);
        y[6] = lg[6] - logf(-logf(u1.z + EPS_G) + EPS_G);
        y[7] = lg[7] - logf(-logf(u1.w + EPS_G) + EPS_G);

        float best = y[0];
        int bi = 0;
#pragma unroll
        for (int v = 1; v < 8; ++v)
            if (y[v] > best) { best = y[v]; bi = v; }   // strict > == np first-max
        idxs_s[g][lane] = bi;
    }
    __syncthreads();

    // pack pair indices: one uint32 per token, coalesced 64-lane store
    if (t < MT) {
        const int tok = t;
        const uint32_t pk =
              (uint32_t)(idxs_s[0][tok] * 8 + idxs_s[1][tok])
            | ((uint32_t)(idxs_s[2][tok] * 8 + idxs_s[3][tok]) << 8)
            | ((uint32_t)(idxs_s[4][tok] * 8 + idxs_s[5][tok]) << 16)
            | ((uint32_t)(idxs_s[6][tok] * 8 + idxs_s[7][tok]) << 24);
        pidx_pack[tokbase + tok] = pk;
    }
}

// ---------------------------------------------------------------------------
// Kernel C: out = b_post + sum_p P2[p][pidx_p]  (standalone gather+store)
// 256 threads / 32 tokens / tiny LDS / low VGPR -> high occupancy.
// Pure L2 gather + streaming nontemporal stores -> HBM write roofline.
// ---------------------------------------------------------------------------
__global__ __launch_bounds__(256) void gather_out(
    const uint32_t* __restrict__ pidx_pack,  // (BT)
    const float* __restrict__ b_post,        // (512)
    const __hip_bfloat16* __restrict__ P2,   // (4,64,512)
    float* __restrict__ out)                 // (BT,512)
{
    __shared__ uint32_t pp[32];
    const int t = threadIdx.x;               // 0..255
    const int tokbase = blockIdx.x * 32;
    if (t < 32) pp[t] = pidx_pack[tokbase + t];
    __syncthreads();

    const int o2 = t * 2;
    const float bp0 = b_post[o2];
    const float bp1 = b_post[o2 + 1];
    const uint32_t* p2u = (const uint32_t*)P2;     // 2 bf16 per uint32
    float* obase = out + (size_t)tokbase * OUT_DIM + o2;

#pragma unroll 4
    for (int tok = 0; tok < 32; ++tok) {
        const uint32_t pk = pp[tok];               // wave-uniform per iteration
        const uint32_t r0 = p2u[(size_t)((pk      ) & 63) * 256 + t];
        const uint32_t r1 = p2u[(size_t)(64  + ((pk >> 8 ) & 63)) * 256 + t];
        const uint32_t r2 = p2u[(size_t)(128 + ((pk >> 16) & 63)) * 256 + t];
        const uint32_t r3 = p2u[(size_t)(192 + ((pk >> 24) & 63)) * 256 + t];
        float s0 = bp0, s1 = bp1;
        s0 += __uint_as_float(r0 << 16); s1 += __uint_as_float(r0 & 0xffff0000u);
        s0 += __uint_as_float(r1 << 16); s1 += __uint_as_float(r1 & 0xffff0000u);
        s0 += __uint_as_float(r2 << 16); s1 += __uint_as_float(r2 & 0xffff0000u);
        s0 += __uint_as_float(r3 << 16); s1 += __uint_as_float(r3 & 0xffff0000u);
        f32x2 sv; sv.x = s0; sv.y = s1;
        __builtin_nontemporal_store(sv, (f32x2*)(obase + (size_t)tok * OUT_DIM));
    }
}

// ---------------------------------------------------------------------------
extern "C" void kernel_launch(void* const* d_in, const int* in_sizes, int n_in,
                              void* d_out, int out_size, void* d_ws, size_t ws_size,
                              hipStream_t stream) {
    const float* x        = (const float*)d_in[0];
    const float* W_pre    = (const float*)d_in[1];
    const float* b_pre    = (const float*)d_in[2];
    const float* W_proj   = (const float*)d_in[3];
    const float* b_proj   = (const float*)d_in[4];
    const float* codebook = (const float*)d_in[5];
    const float* W_post   = (const float*)d_in[6];
    const float* b_post   = (const float*)d_in[7];
    const float* u        = (const float*)d_in[8];
    float* out = (float*)d_out;

    __hip_bfloat16* P2 = (__hip_bfloat16*)d_ws;                       // 256 KB
    uint32_t* pidx     = (uint32_t*)((char*)d_ws + 256 * 1024);       // 128 KB

    build_p2<<<256, 256, 0, stream>>>(codebook, W_post, P2);
    fused_logits<<<BT_TOK / MT, 512, 0, stream>>>(x, W_pre, b_pre, W_proj, b_proj,
                                                  u, pidx);
    gather_out<<<BT_TOK / 32, 256, 0, stream>>>(pidx, b_post, P2, out);
}

// Round 6
// 159.539 us; speedup vs baseline: 1.0033x; 1.0033x over previous
//
#include <hip/hip_runtime.h>
#include <hip/hip_bf16.h>
#include <stdint.h>
#include <stddef.h>

// Problem constants
#define BT_TOK   32768      // B*T
#define IN_DIM   512
#define OUT_DIM  512
#define QDIM     32
#define NG       8
#define NV       8
#define VD       64
#define EPS_G    1e-10f

#define MT       64         // tokens per block (= lanes per wave)
#define NW       8          // waves per block = K-split factor

typedef float f32x2 __attribute__((ext_vector_type(2)));   // native vector for nontemporal store
typedef float f32x4n __attribute__((ext_vector_type(4)));  // native vector for asm loads

// ---------------------------------------------------------------------------
// Kernel A: paired codebook-output table (UNCHANGED — bitwise-identical P2)
// P2[p][i*8+j][o] = cb[2p][i]@W_post[2p*64:...] + cb[2p+1][j]@W_post[...]
// bf16, 4*64*512 = 256 KB in d_ws. Rebuilt every call (ws is re-poisoned).
// ---------------------------------------------------------------------------
__global__ __launch_bounds__(256) void build_p2(
    const float* __restrict__ codebook,   // (8,8,64)
    const float* __restrict__ W_post,     // (512,512)
    __hip_bfloat16* __restrict__ P2)
{
    const int b  = blockIdx.x;     // 0..255
    const int p  = b >> 6;         // pair 0..3
    const int ij = b & 63;
    const int i  = ij >> 3, j = ij & 7;
    const int t  = threadIdx.x;    // 0..255

    const float* ca  = codebook + ((size_t)(2 * p) * NV + i) * VD;
    const float* cbp = codebook + ((size_t)(2 * p + 1) * NV + j) * VD;
    const float* wa  = W_post + (size_t)(2 * p) * VD * OUT_DIM;
    const float* wb  = W_post + (size_t)(2 * p + 1) * VD * OUT_DIM;

    float a0 = 0.f, a1 = 0.f;
#pragma unroll 8
    for (int d = 0; d < VD; ++d) {
        const float sa = ca[d];            // block-uniform -> scalar
        const float sb = cbp[d];
        a0 += sa * wa[(size_t)d * OUT_DIM + t]       + sb * wb[(size_t)d * OUT_DIM + t];
        a1 += sa * wa[(size_t)d * OUT_DIM + t + 256] + sb * wb[(size_t)d * OUT_DIM + t + 256];
    }
    __hip_bfloat16* dst = P2 + ((size_t)(p * 64 + ij)) * OUT_DIM;
    dst[t]       = __float2bfloat16(a0);
    dst[t + 256] = __float2bfloat16(a1);
}

// ---------------------------------------------------------------------------
// Kernel B: h = x@W_pre+b_pre ; logits = h@W_proj+b_proj ;
//           idx = argmax(logits+gumbel(u)) ; emit packed pair-indices.
// Block: 512 threads = 8 waves, 64 tokens. lane = token; wave = K-eighth.
//
// ROUND-6 CHANGE: rounds 3/5 proved the compiler re-sinks pre-issued loads
// regardless of source order or sched_barrier (VGPR stuck at 52, 2-3 loads
// in flight, 75% of the kernel = latency stall). Escalated to INLINE-ASM
// global_load_dwordx4: 18 volatile asm loads issued back-to-back at entry
// (cannot be sunk; dests forced live), with COUNTED s_waitcnt vmcnt(10/2)
// before each stage's ds_writes and vmcnt(0) only before the u consume.
// HipKittens' pattern. Arithmetic order bitwise-identical to rounds 0-5.
// ---------------------------------------------------------------------------
__global__ __launch_bounds__(512, 4) void fused_logits(
    const float* __restrict__ x,        // (BT,512)
    const float* __restrict__ W_pre,    // (512,32)
    const float* __restrict__ b_pre,    // (32)
    const float* __restrict__ W_proj,   // (32,64)
    const float* __restrict__ b_proj,   // (64)
    const float* __restrict__ u,        // (BT,64)
    uint32_t* __restrict__ pidx_pack)   // (BT) packed p0|p1<<8|p2<<16|p3<<24
{
    // Per-wave arena: rows 0..63 (token), 36-float stride. Used first as x
    // stage (cols 0..31 = 32 k-values), then overwritten by partial-h slice.
    __shared__ float Hs4[NW][MT][36];
    __shared__ int   idxs_s[NG][MT];    // argmax per (group, token)

    const int t    = threadIdx.x;
    const int lane = t & 63;                                   // token within block
    const int w    = __builtin_amdgcn_readfirstlane(t >> 6);   // wave id = K-eighth / group
    const int tokbase = blockIdx.x * MT;
    const int gtok    = tokbase + lane;

    const int tsub = lane >> 3;          // token sub-index within 8-token group
    const int c4   = lane & 7;           // 16B chunk within the 128B row slice
    const float* xws = x + (size_t)tokbase * IN_DIM + w * 64;  // wave k-slice base

    // ---- pre-issue ALL 18 global loads as volatile asm (unsinkable) -------
    // Queue order: xv[0..7] (stage 0), xv[8..15] (stage 1), u0, u1.
    f32x4n xv[16];
    f32x4n u0v, u1v;
#pragma unroll
    for (int i = 0; i < 8; ++i) {
        const float* a = xws + (size_t)(i * 8 + tsub) * IN_DIM + c4 * 4;
        asm volatile("global_load_dwordx4 %0, %1, off"
                     : "=&v"(xv[i]) : "v"(a));
    }
#pragma unroll
    for (int i = 0; i < 8; ++i) {
        const float* a = xws + (size_t)(i * 8 + tsub) * IN_DIM + c4 * 4;
        asm volatile("global_load_dwordx4 %0, %1, off offset:128"   // +32 floats = stage 1
                     : "=&v"(xv[8 + i]) : "v"(a));
    }
    {
        const float* ua = &u[(size_t)gtok * 64 + w * 8];
        asm volatile("global_load_dwordx4 %0, %2, off\n\t"
                     "global_load_dwordx4 %1, %2, off offset:16"
                     : "=&v"(u0v), "=&v"(u1v)
                     : "v"(ua));
    }

    // ---------------- Phase 1: partial h over K-slice [w*64, w*64+64) --------
    float acc[QDIM];
#pragma unroll
    for (int j = 0; j < QDIM; ++j) acc[j] = 0.f;

    // consume helper: lane reads ITS token's 32 staged k-values; W_pre rows
    // are wave-uniform -> scalar loads. k ascending (bitwise-identical h).
    auto consume = [&](int s) {
        const float* wbase = W_pre + (size_t)(w * 64 + s * 32) * QDIM;
#pragma unroll
        for (int k4 = 0; k4 < 8; ++k4) {
            const float4 xr = *(const float4*)&Hs4[w][lane][k4 * 4];
            const float xk4[4] = {xr.x, xr.y, xr.z, xr.w};
#pragma unroll
            for (int e = 0; e < 4; ++e) {
                const float xvv = xk4[e];
                const float4* wr = (const float4*)(wbase + (size_t)(k4 * 4 + e) * QDIM); // uniform
                const float4 w0 = wr[0], w1 = wr[1], w2 = wr[2], w3 = wr[3];
                const float4 w4 = wr[4], w5 = wr[5], w6 = wr[6], w7 = wr[7];
                acc[0]  += xvv * w0.x; acc[1]  += xvv * w0.y; acc[2]  += xvv * w0.z; acc[3]  += xvv * w0.w;
                acc[4]  += xvv * w1.x; acc[5]  += xvv * w1.y; acc[6]  += xvv * w1.z; acc[7]  += xvv * w1.w;
                acc[8]  += xvv * w2.x; acc[9]  += xvv * w2.y; acc[10] += xvv * w2.z; acc[11] += xvv * w2.w;
                acc[12] += xvv * w3.x; acc[13] += xvv * w3.y; acc[14] += xvv * w3.z; acc[15] += xvv * w3.w;
                acc[16] += xvv * w4.x; acc[17] += xvv * w4.y; acc[18] += xvv * w4.z; acc[19] += xvv * w4.w;
                acc[20] += xvv * w5.x; acc[21] += xvv * w5.y; acc[22] += xvv * w5.z; acc[23] += xvv * w5.w;
                acc[24] += xvv * w6.x; acc[25] += xvv * w6.y; acc[26] += xvv * w6.z; acc[27] += xvv * w6.w;
                acc[28] += xvv * w7.x; acc[29] += xvv * w7.y; acc[30] += xvv * w7.z; acc[31] += xvv * w7.w;
            }
        }
    };

    // ---- stage 0: wait ONLY for xv[0..7] (10 loads may stay in flight) ----
    asm volatile("s_waitcnt vmcnt(10)" ::: "memory");
    __builtin_amdgcn_sched_barrier(0);
#pragma unroll
    for (int i = 0; i < 8; ++i)
        *(f32x4n*)&Hs4[w][i * 8 + tsub][c4 * 4] = xv[i];
    consume(0);

    // ---- stage 1: wait for xv[8..15] (u0,u1 still in flight) --------------
    asm volatile("s_waitcnt vmcnt(2)" ::: "memory");
    __builtin_amdgcn_sched_barrier(0);
#pragma unroll
    for (int i = 0; i < 8; ++i)
        *(f32x4n*)&Hs4[w][i * 8 + tsub][c4 * 4] = xv[8 + i];
    consume(1);

    // write partials over the stage data (b128; stride-36 layout)
#pragma unroll
    for (int j4 = 0; j4 < 8; ++j4)
        *(float4*)&Hs4[w][lane][j4 * 4] =
            make_float4(acc[j4 * 4], acc[j4 * 4 + 1], acc[j4 * 4 + 2], acc[j4 * 4 + 3]);
    __syncthreads();

    // reduce 8 K-slices in place (each cell owned by exactly one thread)
#pragma unroll
    for (int r = 0; r < 4; ++r) {
        const int id  = t + 512 * r;          // 2048 (tok,j) cells
        const int tok = id >> 5;
        const int j   = id & 31;
        float h = b_pre[j];
#pragma unroll
        for (int q = 0; q < NW; ++q) h += Hs4[q][tok][j];
        Hs4[0][tok][j] = h;
    }
    __syncthreads();

    // ---------------- Phase 2: logits + gumbel + argmax (wave w -> group w) ---
    float h[QDIM];
#pragma unroll
    for (int j4 = 0; j4 < 8; ++j4) {
        const float4 v = *(const float4*)&Hs4[0][lane][j4 * 4];
        h[j4 * 4] = v.x; h[j4 * 4 + 1] = v.y; h[j4 * 4 + 2] = v.z; h[j4 * 4 + 3] = v.w;
    }

    {
        const int g = w;                                // wave-uniform group
        const float4 b0 = *(const float4*)&b_proj[g * 8];
        const float4 b1 = *(const float4*)&b_proj[g * 8 + 4];
        float lg[8] = {b0.x, b0.y, b0.z, b0.w, b1.x, b1.y, b1.z, b1.w};

#pragma unroll
        for (int j = 0; j < QDIM; ++j) {
            const float hv = h[j];
            const float4 a0 = *(const float4*)&W_proj[(size_t)j * 64 + g * 8];     // uniform
            const float4 a1 = *(const float4*)&W_proj[(size_t)j * 64 + g * 8 + 4]; // uniform
            lg[0] += hv * a0.x; lg[1] += hv * a0.y; lg[2] += hv * a0.z; lg[3] += hv * a0.w;
            lg[4] += hv * a1.x; lg[5] += hv * a1.y; lg[6] += hv * a1.z; lg[7] += hv * a1.w;
        }

        // u0v/u1v arrived long ago (and __syncthreads drained vmcnt); the
        // explicit wait is a no-op guard against reg-only consumer hoisting.
        asm volatile("s_waitcnt vmcnt(0)" ::: "memory");
        __builtin_amdgcn_sched_barrier(0);

        float y[8];
        y[0] = lg[0] - logf(-logf(u0v[0] + EPS_G) + EPS_G);
        y[1] = lg[1] - logf(-logf(u0v[1] + EPS_G) + EPS_G);
        y[2] = lg[2] - logf(-logf(u0v[2] + EPS_G) + EPS_G);
        y[3] = lg[3] - logf(-logf(u0v[3] + EPS_G) + EPS_G);
        y[4] = lg[4] - logf(-logf(u1v[0] + EPS_G) + EPS_G);
        y[5] = lg[5] - logf(-logf(u1v[1] + EPS_G) + EPS_G);
        y[6] = lg[6] - logf(-logf(u1v[2] + EPS_G) + EPS_G);
        y[7] = lg[7] - logf(-logf(u1v[3] + EPS_G) + EPS_G);

        float best = y[0];
        int bi = 0;
#pragma unroll
        for (int v = 1; v < 8; ++v)
            if (y[v] > best) { best = y[v]; bi = v; }   // strict > == np first-max
        idxs_s[g][lane] = bi;
    }
    __syncthreads();

    // pack pair indices: one uint32 per token, coalesced 64-lane store
    if (t < MT) {
        const int tok = t;
        const uint32_t pk =
              (uint32_t)(idxs_s[0][tok] * 8 + idxs_s[1][tok])
            | ((uint32_t)(idxs_s[2][tok] * 8 + idxs_s[3][tok]) << 8)
            | ((uint32_t)(idxs_s[4][tok] * 8 + idxs_s[5][tok]) << 16)
            | ((uint32_t)(idxs_s[6][tok] * 8 + idxs_s[7][tok]) << 24);
        pidx_pack[tokbase + tok] = pk;
    }
}

// ---------------------------------------------------------------------------
// Kernel C: out = b_post + sum_p P2[p][pidx_p]  (standalone gather+store)
// 256 threads / 32 tokens / tiny LDS / low VGPR -> high occupancy.
// Pure L2 gather + streaming nontemporal stores -> HBM write roofline.
// ---------------------------------------------------------------------------
__global__ __launch_bounds__(256) void gather_out(
    const uint32_t* __restrict__ pidx_pack,  // (BT)
    const float* __restrict__ b_post,        // (512)
    const __hip_bfloat16* __restrict__ P2,   // (4,64,512)
    float* __restrict__ out)                 // (BT,512)
{
    __shared__ uint32_t pp[32];
    const int t = threadIdx.x;               // 0..255
    const int tokbase = blockIdx.x * 32;
    if (t < 32) pp[t] = pidx_pack[tokbase + t];
    __syncthreads();

    const int o2 = t * 2;
    const float bp0 = b_post[o2];
    const float bp1 = b_post[o2 + 1];
    const uint32_t* p2u = (const uint32_t*)P2;     // 2 bf16 per uint32
    float* obase = out + (size_t)tokbase * OUT_DIM + o2;

#pragma unroll 4
    for (int tok = 0; tok < 32; ++tok) {
        const uint32_t pk = pp[tok];               // wave-uniform per iteration
        const uint32_t r0 = p2u[(size_t)((pk      ) & 63) * 256 + t];
        const uint32_t r1 = p2u[(size_t)(64  + ((pk >> 8 ) & 63)) * 256 + t];
        const uint32_t r2 = p2u[(size_t)(128 + ((pk >> 16) & 63)) * 256 + t];
        const uint32_t r3 = p2u[(size_t)(192 + ((pk >> 24) & 63)) * 256 + t];
        float s0 = bp0, s1 = bp1;
        s0 += __uint_as_float(r0 << 16); s1 += __uint_as_float(r0 & 0xffff0000u);
        s0 += __uint_as_float(r1 << 16); s1 += __uint_as_float(r1 & 0xffff0000u);
        s0 += __uint_as_float(r2 << 16); s1 += __uint_as_float(r2 & 0xffff0000u);
        s0 += __uint_as_float(r3 << 16); s1 += __uint_as_float(r3 & 0xffff0000u);
        f32x2 sv; sv.x = s0; sv.y = s1;
        __builtin_nontemporal_store(sv, (f32x2*)(obase + (size_t)tok * OUT_DIM));
    }
}

// ---------------------------------------------------------------------------
extern "C" void kernel_launch(void* const* d_in, const int* in_sizes, int n_in,
                              void* d_out, int out_size, void* d_ws, size_t ws_size,
                              hipStream_t stream) {
    const float* x        = (const float*)d_in[0];
    const float* W_pre    = (const float*)d_in[1];
    const float* b_pre    = (const float*)d_in[2];
    const float* W_proj   = (const float*)d_in[3];
    const float* b_proj   = (const float*)d_in[4];
    const float* codebook = (const float*)d_in[5];
    const float* W_post   = (const float*)d_in[6];
    const float* b_post   = (const float*)d_in[7];
    const float* u        = (const float*)d_in[8];
    float* out = (float*)d_out;

    __hip_bfloat16* P2 = (__hip_bfloat16*)d_ws;                       // 256 KB
    uint32_t* pidx     = (uint32_t*)((char*)d_ws + 256 * 1024);       // 128 KB

    build_p2<<<256, 256, 0, stream>>>(codebook, W_post, P2);
    fused_logits<<<BT_TOK / MT, 512, 0, stream>>>(x, W_pre, b_pre, W_proj, b_proj,
                                                  u, pidx);
    gather_out<<<BT_TOK / 32, 256, 0, stream>>>(pidx, b_post, P2, out);
}

// Round 7
// 156.905 us; speedup vs baseline: 1.0201x; 1.0168x over previous
//
#include <hip/hip_runtime.h>
#include <hip/hip_bf16.h>
#include <stdint.h>
#include <stddef.h>

// Problem constants
#define BT_TOK   32768      // B*T
#define IN_DIM   512
#define OUT_DIM  512
#define QDIM     32
#define NG       8
#define NV       8
#define VD       64
#define EPS_G    1e-10f

#define MT       64         // tokens per block (= lanes per wave)
#define NW       8          // waves per block = K-split factor

typedef float f32x2 __attribute__((ext_vector_type(2)));   // native vector for nontemporal store

#define AS1 __attribute__((address_space(1)))
#define AS3 __attribute__((address_space(3)))

// Direct global->LDS DMA, 16B per lane, dest = wave-uniform base + lane*16.
// No destination VGPRs exist -> the register allocator cannot sink/spill the
// prefetch (rounds 3/5/6 all lost that fight; round 6 spilled to AGPRs with
// hidden per-load waits). Low 32 bits of a flat LDS pointer are the LDS
// offset (shared-aperture low bits are zero) - CK's cast pattern.
__device__ __forceinline__ void gl_lds16(const float* g, const float* l) {
    __builtin_amdgcn_global_load_lds((AS1 void*)(uintptr_t)g,
                                     (AS3 void*)(uintptr_t)l, 16, 0, 0);
}

// ---------------------------------------------------------------------------
// Kernel A: paired codebook-output table (UNCHANGED — bitwise-identical P2)
// P2[p][i*8+j][o] = cb[2p][i]@W_post[2p*64:...] + cb[2p+1][j]@W_post[...]
// bf16, 4*64*512 = 256 KB in d_ws. Rebuilt every call (ws is re-poisoned).
// ---------------------------------------------------------------------------
__global__ __launch_bounds__(256) void build_p2(
    const float* __restrict__ codebook,   // (8,8,64)
    const float* __restrict__ W_post,     // (512,512)
    __hip_bfloat16* __restrict__ P2)
{
    const int b  = blockIdx.x;     // 0..255
    const int p  = b >> 6;         // pair 0..3
    const int ij = b & 63;
    const int i  = ij >> 3, j = ij & 7;
    const int t  = threadIdx.x;    // 0..255

    const float* ca  = codebook + ((size_t)(2 * p) * NV + i) * VD;
    const float* cbp = codebook + ((size_t)(2 * p + 1) * NV + j) * VD;
    const float* wa  = W_post + (size_t)(2 * p) * VD * OUT_DIM;
    const float* wb  = W_post + (size_t)(2 * p + 1) * VD * OUT_DIM;

    float a0 = 0.f, a1 = 0.f;
#pragma unroll 8
    for (int d = 0; d < VD; ++d) {
        const float sa = ca[d];            // block-uniform -> scalar
        const float sb = cbp[d];
        a0 += sa * wa[(size_t)d * OUT_DIM + t]       + sb * wb[(size_t)d * OUT_DIM + t];
        a1 += sa * wa[(size_t)d * OUT_DIM + t + 256] + sb * wb[(size_t)d * OUT_DIM + t + 256];
    }
    __hip_bfloat16* dst = P2 + ((size_t)(p * 64 + ij)) * OUT_DIM;
    dst[t]       = __float2bfloat16(a0);
    dst[t + 256] = __float2bfloat16(a1);
}

// ---------------------------------------------------------------------------
// Kernel B: h = x@W_pre+b_pre ; logits = h@W_proj+b_proj ;
//           idx = argmax(logits+gumbel(u)) ; emit packed pair-indices.
// Block: 512 threads = 8 waves, 64 tokens. lane = token; wave = K-eighth.
//
// ROUND-7: x staged via __builtin_amdgcn_global_load_lds (register-free DMA).
// LDS arena is UNPADDED [64][32] per wave (gl_lds needs linear dest), so all
// LDS accesses use a 16B-chunk XOR swizzle (chunk ^= row&7) applied on BOTH
// sides: the per-lane GLOBAL source address is pre-swizzled, and every LDS
// read/write applies the same XOR (rule: both-sides-or-neither). Any 8
// consecutive lanes then cover all 32 banks on b128 accesses (~0 conflicts).
// Accumulation order is bitwise-identical to rounds 0-6.
// ---------------------------------------------------------------------------
__global__ __launch_bounds__(512, 4) void fused_logits(
    const float* __restrict__ x,        // (BT,512)
    const float* __restrict__ W_pre,    // (512,32)
    const float* __restrict__ b_pre,    // (32)
    const float* __restrict__ W_proj,   // (32,64)
    const float* __restrict__ b_proj,   // (64)
    const float* __restrict__ u,        // (BT,64)
    uint32_t* __restrict__ pidx_pack)   // (BT) packed p0|p1<<8|p2<<16|p3<<24
{
    // Per-wave arena: rows 0..63 (token), 32-float rows (8 chunks of 16B),
    // XOR-swizzled by row&7. Used first as x stage (32 k-values), then
    // overwritten by the partial-h slice (32 j-values).
    __shared__ float Hs[NW][MT][32];
    __shared__ int   idxs_s[NG][MT];    // argmax per (group, token)

    const int t    = threadIdx.x;
    const int lane = t & 63;                                   // token within block
    const int w    = __builtin_amdgcn_readfirstlane(t >> 6);   // wave id = K-eighth / group
    const int tokbase = blockIdx.x * MT;
    const int gtok    = tokbase + lane;

    const int tsub = lane >> 3;          // token sub-index within 8-token group
    const int c4   = lane & 7;           // 16B chunk within the 128B row slice
    const int csw  = lane & 7;           // swizzle key for row==lane accesses
    const float* xws = x + (size_t)tokbase * IN_DIM + w * 64;  // wave k-slice base

    // ---------------- Phase 1: partial h over K-slice [w*64, w*64+64) --------
    float acc[QDIM];
#pragma unroll
    for (int j = 0; j < QDIM; ++j) acc[j] = 0.f;

#pragma unroll
    for (int s = 0; s < 2; ++s) {        // 2 stages of 32 k
        // Stage: 8 direct-to-LDS loads. Instr i covers rows [8i,8i+8); lane l
        // lands at row 8i+(l>>3), LDS chunk l&7. Source chunk pre-swizzled so
        // LDS chunk p of row r holds data chunk p^(r&7)  (r&7 == tsub).
        const float* xs = xws + s * 32;
#pragma unroll
        for (int i = 0; i < 8; ++i)
            gl_lds16(xs + (size_t)(i * 8 + tsub) * IN_DIM + ((c4 ^ tsub) * 4),
                     &Hs[w][i * 8][0]);
        asm volatile("s_waitcnt vmcnt(0)" ::: "memory");
        __builtin_amdgcn_sched_barrier(0);

        // Consume: lane reads ITS token's 32 staged k-values (swizzled chunk
        // addressing); W_pre rows wave-uniform -> scalar loads. k ascending
        // (bitwise-identical h).
        const float* wbase = W_pre + (size_t)(w * 64 + s * 32) * QDIM;
#pragma unroll
        for (int k4 = 0; k4 < 8; ++k4) {
            const float4 xr = *(const float4*)&Hs[w][lane][(k4 ^ csw) * 4];
            const float xk4[4] = {xr.x, xr.y, xr.z, xr.w};
#pragma unroll
            for (int e = 0; e < 4; ++e) {
                const float xvv = xk4[e];
                const float4* wr = (const float4*)(wbase + (size_t)(k4 * 4 + e) * QDIM); // uniform
                const float4 w0 = wr[0], w1 = wr[1], w2 = wr[2], w3 = wr[3];
                const float4 w4 = wr[4], w5 = wr[5], w6 = wr[6], w7 = wr[7];
                acc[0]  += xvv * w0.x; acc[1]  += xvv * w0.y; acc[2]  += xvv * w0.z; acc[3]  += xvv * w0.w;
                acc[4]  += xvv * w1.x; acc[5]  += xvv * w1.y; acc[6]  += xvv * w1.z; acc[7]  += xvv * w1.w;
                acc[8]  += xvv * w2.x; acc[9]  += xvv * w2.y; acc[10] += xvv * w2.z; acc[11] += xvv * w2.w;
                acc[12] += xvv * w3.x; acc[13] += xvv * w3.y; acc[14] += xvv * w3.z; acc[15] += xvv * w3.w;
                acc[16] += xvv * w4.x; acc[17] += xvv * w4.y; acc[18] += xvv * w4.z; acc[19] += xvv * w4.w;
                acc[20] += xvv * w5.x; acc[21] += xvv * w5.y; acc[22] += xvv * w5.z; acc[23] += xvv * w5.w;
                acc[24] += xvv * w6.x; acc[25] += xvv * w6.y; acc[26] += xvv * w6.z; acc[27] += xvv * w6.w;
                acc[28] += xvv * w7.x; acc[29] += xvv * w7.y; acc[30] += xvv * w7.z; acc[31] += xvv * w7.w;
            }
        }
        // Stage-1 DMA writes target rows just read; gl_lds is a memory write
        // to the same arena -> compiler preserves read->write order, and the
        // sched_barrier above pins the wait.
    }

    // write partials over the stage data (b128, swizzled chunks)
#pragma unroll
    for (int j4 = 0; j4 < 8; ++j4)
        *(float4*)&Hs[w][lane][(j4 ^ csw) * 4] =
            make_float4(acc[j4 * 4], acc[j4 * 4 + 1], acc[j4 * 4 + 2], acc[j4 * 4 + 3]);
    __syncthreads();

    // reduce 8 K-slices in place (each cell owned by exactly one thread).
    // Cell (tok,j) lives at chunk (j>>2)^(tok&7), element j&3.
#pragma unroll
    for (int r = 0; r < 4; ++r) {
        const int id  = t + 512 * r;          // 2048 (tok,j) cells
        const int tok = id >> 5;
        const int j   = id & 31;
        const int sw  = ((j >> 2) ^ (tok & 7)) * 4 + (j & 3);
        float h = b_pre[j];
#pragma unroll
        for (int q = 0; q < NW; ++q) h += Hs[q][tok][sw];
        Hs[0][tok][sw] = h;
    }
    __syncthreads();

    // ---------------- Phase 2: logits + gumbel + argmax (wave w -> group w) ---
    float h[QDIM];
#pragma unroll
    for (int j4 = 0; j4 < 8; ++j4) {
        const float4 v = *(const float4*)&Hs[0][lane][(j4 ^ csw) * 4];
        h[j4 * 4] = v.x; h[j4 * 4 + 1] = v.y; h[j4 * 4 + 2] = v.z; h[j4 * 4 + 3] = v.w;
    }

    {
        const int g = w;                                // wave-uniform group
        const float4 b0 = *(const float4*)&b_proj[g * 8];
        const float4 b1 = *(const float4*)&b_proj[g * 8 + 4];
        float lg[8] = {b0.x, b0.y, b0.z, b0.w, b1.x, b1.y, b1.z, b1.w};

#pragma unroll
        for (int j = 0; j < QDIM; ++j) {
            const float hv = h[j];
            const float4 a0 = *(const float4*)&W_proj[(size_t)j * 64 + g * 8];     // uniform
            const float4 a1 = *(const float4*)&W_proj[(size_t)j * 64 + g * 8 + 4]; // uniform
            lg[0] += hv * a0.x; lg[1] += hv * a0.y; lg[2] += hv * a0.z; lg[3] += hv * a0.w;
            lg[4] += hv * a1.x; lg[5] += hv * a1.y; lg[6] += hv * a1.z; lg[7] += hv * a1.w;
        }

        const float4 u0 = *(const float4*)&u[(size_t)gtok * 64 + g * 8];
        const float4 u1 = *(const float4*)&u[(size_t)gtok * 64 + g * 8 + 4];
        float y[8];
        y[0] = lg[0] - logf(-logf(u0.x + EPS_G) + EPS_G);
        y[1] = lg[1] - logf(-logf(u0.y + EPS_G) + EPS_G);
        y[2] = lg[2] - logf(-logf(u0.z + EPS_G) + EPS_G);
        y[3] = lg[3] - logf(-logf(u0.w + EPS_G) + EPS_G);
        y[4] = lg[4] - logf(-logf(u1.x + EPS_G) + EPS_G);
        y[5] = lg[5] - logf(-logf(u1.y + EPS_G) + EPS_G);
        y[6] = lg[6] - logf(-logf(u1.z + EPS_G) + EPS_G);
        y[7] = lg[7] - logf(-logf(u1.w + EPS_G) + EPS_G);

        float best = y[0];
        int bi = 0;
#pragma unroll
        for (int v = 1; v < 8; ++v)
            if (y[v] > best) { best = y[v]; bi = v; }   // strict > == np first-max
        idxs_s[g][lane] = bi;
    }
    __syncthreads();

    // pack pair indices: one uint32 per token, coalesced 64-lane store
    if (t < MT) {
        const int tok = t;
        const uint32_t pk =
              (uint32_t)(idxs_s[0][tok] * 8 + idxs_s[1][tok])
            | ((uint32_t)(idxs_s[2][tok] * 8 + idxs_s[3][tok]) << 8)
            | ((uint32_t)(idxs_s[4][tok] * 8 + idxs_s[5][tok]) << 16)
            | ((uint32_t)(idxs_s[6][tok] * 8 + idxs_s[7][tok]) << 24);
        pidx_pack[tokbase + tok] = pk;
    }
}

// ---------------------------------------------------------------------------
// Kernel C: out = b_post + sum_p P2[p][pidx_p]  (standalone gather+store)
// 256 threads / 32 tokens / tiny LDS / low VGPR -> high occupancy.
// Pure L2 gather + streaming nontemporal stores -> HBM write roofline.
// ---------------------------------------------------------------------------
__global__ __launch_bounds__(256) void gather_out(
    const uint32_t* __restrict__ pidx_pack,  // (BT)
    const float* __restrict__ b_post,        // (512)
    const __hip_bfloat16* __restrict__ P2,   // (4,64,512)
    float* __restrict__ out)                 // (BT,512)
{
    __shared__ uint32_t pp[32];
    const int t = threadIdx.x;               // 0..255
    const int tokbase = blockIdx.x * 32;
    if (t < 32) pp[t] = pidx_pack[tokbase + t];
    __syncthreads();

    const int o2 = t * 2;
    const float bp0 = b_post[o2];
    const float bp1 = b_post[o2 + 1];
    const uint32_t* p2u = (const uint32_t*)P2;     // 2 bf16 per uint32
    float* obase = out + (size_t)tokbase * OUT_DIM + o2;

#pragma unroll 4
    for (int tok = 0; tok < 32; ++tok) {
        const uint32_t pk = pp[tok];               // wave-uniform per iteration
        const uint32_t r0 = p2u[(size_t)((pk      ) & 63) * 256 + t];
        const uint32_t r1 = p2u[(size_t)(64  + ((pk >> 8 ) & 63)) * 256 + t];
        const uint32_t r2 = p2u[(size_t)(128 + ((pk >> 16) & 63)) * 256 + t];
        const uint32_t r3 = p2u[(size_t)(192 + ((pk >> 24) & 63)) * 256 + t];
        float s0 = bp0, s1 = bp1;
        s0 += __uint_as_float(r0 << 16); s1 += __uint_as_float(r0 & 0xffff0000u);
        s0 += __uint_as_float(r1 << 16); s1 += __uint_as_float(r1 & 0xffff0000u);
        s0 += __uint_as_float(r2 << 16); s1 += __uint_as_float(r2 & 0xffff0000u);
        s0 += __uint_as_float(r3 << 16); s1 += __uint_as_float(r3 & 0xffff0000u);
        f32x2 sv; sv.x = s0; sv.y = s1;
        __builtin_nontemporal_store(sv, (f32x2*)(obase + (size_t)tok * OUT_DIM));
    }
}

// ---------------------------------------------------------------------------
extern "C" void kernel_launch(void* const* d_in, const int* in_sizes, int n_in,
                              void* d_out, int out_size, void* d_ws, size_t ws_size,
                              hipStream_t stream) {
    const float* x        = (const float*)d_in[0];
    const float* W_pre    = (const float*)d_in[1];
    const float* b_pre    = (const float*)d_in[2];
    const float* W_proj   = (const float*)d_in[3];
    const float* b_proj   = (const float*)d_in[4];
    const float* codebook = (const float*)d_in[5];
    const float* W_post   = (const float*)d_in[6];
    const float* b_post   = (const float*)d_in[7];
    const float* u        = (const float*)d_in[8];
    float* out = (float*)d_out;

    __hip_bfloat16* P2 = (__hip_bfloat16*)d_ws;                       // 256 KB
    uint32_t* pidx     = (uint32_t*)((char*)d_ws + 256 * 1024);       // 128 KB

    build_p2<<<256, 256, 0, stream>>>(codebook, W_post, P2);
    fused_logits<<<BT_TOK / MT, 512, 0, stream>>>(x, W_pre, b_pre, W_proj, b_proj,
                                                  u, pidx);
    gather_out<<<BT_TOK / 32, 256, 0, stream>>>(pidx, b_post, P2, out);
}